// Round 6
// baseline (336.246 us; speedup 1.0000x reference)
//
#include <hip/hip_runtime.h>

// ---------------- problem constants ----------------
#define B_  8
#define C_  32
#define U_  5
#define V_  5
#define H_  64
#define W_  64

// x / out strides (fp32 elements): [B][32][U][V][H][W]
#define SV_ 4096
#define SU_ 20480
#define SC_ 102400
#define SB_ 3276800

// xT (bf16, padded): [row = ((b*25+u*5+v)*64+h)][cq(4)][wslot(66)][c8(8)]
//   wslot = w+1 ; slots 0 and 65 are zeros (SAME padding in w for free)
//   row stride = 4*66*16 = 4224 B ; total 12800*4224 = 54067200 B
//
// Weight table (paired A-frags, rows0-7 = branch lo, rows8-15 = branch hi).
// LDS image = global bytes [0, 53376). Region ends verified:
//   FULL [0, 15360):      15 frags x 1024 B, layout [q(4)][row(16)][j(8)]
//     f 0..8  : T01 center (t=1 | dw=1): rows0-7 br0(du,dv,1), rows8-15 br1(du,dv,1)
//     f 9..14 : T23 center (du=1,dv=1) idx=a*3+bb<=5: rows0-7 br2, rows8-15 br3
//   LO   [15360, 34368):  36 frags x 528 B = 512 data [q][oc8][j8] + 16 B zero pad
//     g 0..17 : T01 br0 singles (du,dv)x{t=0,t=2}   (rows8-15 lanes read the pad)
//     g 18..35: T23 br2 singles (dv==1, du in {0,2}) x (a,b)
//   HI   [34368, 53376):  36 frags x 528 B          (rows0-7 lanes read the pad)
//     g 0..17 : T01 br1 singles (du,dv)x{dw=0,dw=2}
//     g 18..35: T23 br3 singles (du==1, dv in {0,2}) x (a,b)
//   GLOBAL-ONLY [53376, 56448): FULL idx 6,7,8 (T23c a=2, bb=0,1,2), 1024 B each
#define XROW 4224
#define BT_OFF 54067200ull
#define LDS_BYTES 53376
#define LO_BASE 15360
#define HI_BASE 34368
#define GF_OFF 53376

typedef short bf16x8 __attribute__((ext_vector_type(8)));
typedef float f32x4 __attribute__((ext_vector_type(4)));

__device__ __forceinline__ unsigned short f2bf(float f) {
    unsigned int u = __builtin_bit_cast(unsigned int, f);
    u = (u + 0x7FFFu + ((u >> 16) & 1u)) >> 16;   // RNE
    return (unsigned short)u;
}

__device__ __forceinline__ f32x4 mfma16(bf16x8 a, bf16x8 b, f32x4 c) {
    return __builtin_amdgcn_mfma_f32_16x16x32_bf16(a, b, c, 0, 0, 0);
}

// ---------------- K1: prep = transpose (blocks 0..3199) + weight table (3200..3289) ----
__global__ __launch_bounds__(256)
void k_prep(const float* __restrict__ x, unsigned short* __restrict__ xT,
            const float* __restrict__ w0, const float* __restrict__ w1,
            const float* __restrict__ w2, const float* __restrict__ w3,
            unsigned short* __restrict__ btab)
{
    if (blockIdx.x >= 3200) {
        const int f = blockIdx.x - 3200;   // 0..89
        const int tid = threadIdx.x;
        if (f < 18) {
            // FULL frag: 512 entries [q][row16][j8]; f<15 -> LDS image, else global-only
            const size_t base = (f < 15) ? (size_t)f * 512
                                         : (GF_OFF / 2 + (size_t)(f - 15) * 512);
            for (int e = tid; e < 512; e += 256) {
                const int q = e >> 7, row = (e >> 3) & 15, j = e & 7;
                const int c = q * 8 + j;
                float val;
                if (f < 9) {          // T01 center: du=f/3, dv=f%3, tap *,*,1
                    const int tap = (f / 3) * 9 + (f % 3) * 3 + 1;
                    val = (row < 8) ? w0[row * 864 + c * 27 + tap]
                                    : w1[(row - 8) * 864 + c * 27 + tap];
                } else {              // T23 center: du=dv=1, tap 1,a,b  (idx = f-9)
                    const int tap = 9 + (f - 9);
                    val = (row < 8) ? w2[row * 864 + c * 27 + tap]
                                    : w3[(row - 8) * 864 + c * 27 + tap];
                }
                btab[base + e] = f2bf(val);
            }
        } else {
            const bool hi = (f >= 54);
            const int g = hi ? (f - 54) : (f - 18);        // 0..35
            const size_t base = (hi ? HI_BASE : LO_BASE) / 2 + (size_t)g * 264;
            for (int e = tid; e < 264; e += 256) {
                unsigned short outv = 0;                    // zero pad entries 256..263
                if (e < 256) {
                    const int q = e >> 6, oc = (e >> 3) & 7, j = e & 7;
                    const int c = q * 8 + j;
                    float val;
                    if (g < 18) {     // T01 singles: pair p=(du,dv), tap offset which*2
                        const int p = g >> 1, which = g & 1;
                        const int tap = (p / 3) * 9 + (p % 3) * 3 + which * 2;
                        val = hi ? w1[oc * 864 + c * 27 + tap]      // br1, dw=0/2
                                 : w0[oc * 864 + c * 27 + tap];     // br0, t =0/2
                    } else {          // T23 singles: outer = 0 or 2, tap outer,a,b
                        const int h2 = g - 18;
                        const int tap = (h2 / 9) * 18 + (h2 % 9);   // outer*9 + a*3+b
                        val = hi ? w3[oc * 864 + c * 27 + tap]      // br3 (du==1)
                                 : w2[oc * 864 + c * 27 + tap];     // br2 (dv==1)
                    }
                    outv = f2bf(val);
                }
                btab[base + e] = outv;
            }
        }
        return;
    }

    // ---- x fp32 [B,C,U,V,H,W] -> padded bf16 xT ----
    __shared__ float tl[C_ * 4 * 64];   // [c][h(4)][w(64)] fp32, 32 KB
    const int tid = threadIdx.x;
    int blk = blockIdx.x;
    const int hq = blk & 15; blk >>= 4;
    const int v = blk % 5; blk /= 5;
    const int u = blk % 5;
    const int b = blk / 5;
    const int h0 = hq * 4;

    const float* src = x + (size_t)b * SB_ + (size_t)u * SU_ + (size_t)v * SV_ + h0 * 64;
#pragma unroll
    for (int i = 0; i < 8; ++i) {
        const int e = tid + i * 256;
        const int c = e >> 6;
        const int rem = e & 63;
        const int h = rem >> 4;
        const int w4 = (rem & 15) * 4;
        const float4 val = *(const float4*)(src + (size_t)c * SC_ + h * 64 + w4);
        *(float4*)(tl + c * 256 + h * 64 + w4) = val;
    }
    __syncthreads();

    const int h = tid >> 6;
    const int w = tid & 63;
    unsigned short* dst = xT + (size_t)((b * 25 + u * 5 + v) * 64 + h0 + h) * (XROW / 2);
    const uint4 z = make_uint4(0u, 0u, 0u, 0u);
#pragma unroll
    for (int cq = 0; cq < 4; ++cq) {
        unsigned short s[8];
#pragma unroll
        for (int j = 0; j < 8; ++j)
            s[j] = f2bf(tl[(cq * 8 + j) * 256 + h * 64 + w]);
        uint4 o;
        o.x = (unsigned)s[0] | ((unsigned)s[1] << 16);
        o.y = (unsigned)s[2] | ((unsigned)s[3] << 16);
        o.z = (unsigned)s[4] | ((unsigned)s[5] << 16);
        o.w = (unsigned)s[6] | ((unsigned)s[7] << 16);
        *(uint4*)(dst + cq * 528 + (w + 1) * 8) = o;           // wslot = w+1
        if (w == 0)  *(uint4*)(dst + cq * 528 + 0)       = z;  // wslot 0
        if (w == 63) *(uint4*)(dst + cq * 528 + 65 * 8)  = z;  // wslot 65
    }
}

// ---------------- K2: main MFMA kernel (8 h-rows per wave) ----
// grid 800 = 8 b * 25 buv * 4 hs16 ; block 512 thr = 8 waves = 4 w-tiles x 2 h-groups.
// XCD-chunked: XCD (blk&7) owns batch b=(blk&7); hs fastest keeps (u,v) 9-neighborhood
// in that XCD's L2. wave: w-tile (wave&3)*16, h-octet hb = hs*16 + (wave>>2)*8.
// Per (du,dv,bb): ONE 10-row window R[r] = x-row hb-1+r; uniform index R[t+hh], hh 0..7.
//   -> each weight ds_read feeds 8 mfmas (LDS pipe halved vs 4-row waves);
//   -> 10 row-loads per bb instead of 2x6; staging per output halved (800 blocks).
// Regs: R 40 + W <=16 + addr ~10 = ~64 arch + 64 acc = 128 -> 4 waves/SIMD.
// launch_bounds(512,4) caps unified at 128 (tiny squeeze; R3-style 85-cap forbidden).
__global__ __launch_bounds__(512, 4)
void k_main(const unsigned short* __restrict__ xT,
            const unsigned short* __restrict__ btabu,
            const float* __restrict__ bb0, const float* __restrict__ aa0,
            const float* __restrict__ bb1, const float* __restrict__ aa1,
            const float* __restrict__ bb2, const float* __restrict__ aa2,
            const float* __restrict__ bb3, const float* __restrict__ aa3,
            float* __restrict__ out)
{
    __shared__ alignas(16) char wlds[LDS_BYTES];

    const int tid = threadIdx.x;
    const int blk = blockIdx.x;
    const int b   = blk & 7;          // == XCD id
    const int i   = blk >> 3;         // 0..99
    const int buv = i >> 2;           // 0..24
    const int hs  = i & 3;
    const int v = buv % 5;
    const int u = buv / 5;
    const int h0 = hs * 16;

    // stage weight table to LDS (one time): 53376/16 = 3336 uint4
    {
        const uint4* g = (const uint4*)btabu;
        uint4* l = (uint4*)wlds;
#pragma unroll
        for (int it = 0; it < 7; ++it) {
            const int e = tid + it * 512;
            if (e < 3336) l[e] = g[e];
        }
    }
    __syncthreads();   // the only barrier

    const int wave = tid >> 6;
    const int lane = tid & 63;
    const int n = lane & 15;
    const int q = lane >> 4;
    const int w0 = (wave & 3) * 16;
    const int hb = h0 + (wave >> 2) * 8;
    const int hbu = __builtin_amdgcn_readfirstlane(hb);   // wave-uniform -> SGPR

    f32x4 acc01[8], acc23[8];
#pragma unroll
    for (int j = 0; j < 8; ++j) { acc01[j] = (f32x4)0.f; acc23[j] = (f32x4)0.f; }

    const char* xTb = (const char*)xT;
    const int lane_off = q * 1056 + (w0 + n) * 16;

    // per-lane A-frag offsets (computed once; frag index folds to imm offset)
    const int off_full = q * 256 + n * 16;                           // FULL [q][row16][j]
    const int off_lo   = (n < 8) ? (q * 128 + n * 16) : 512;         // data | frag zero pad
    const int off_hi   = (n < 8) ? 512 : (q * 128 + (n & 7) * 16);   // frag zero pad | data

    auto RF = [&](int f) -> bf16x8 {            // f = 0..14 (LDS)
        return *(const bf16x8*)(wlds + f * 1024 + off_full);
    };
    auto GF = [&](int k) -> bf16x8 {            // k = 0..2 (global-only T23c a=2)
        return *(const bf16x8*)((const char*)btabu + GF_OFF + k * 1024 + off_full);
    };
    auto RL = [&](int g) -> bf16x8 {
        return *(const bf16x8*)(wlds + LO_BASE + g * 528 + off_lo);
    };
    auto RH = [&](int g) -> bf16x8 {
        return *(const bf16x8*)(wlds + HI_BASE + g * 528 + off_hi);
    };
    const bf16x8 zf = {0, 0, 0, 0, 0, 0, 0, 0};

#pragma unroll
    for (int du = 0; du < 3; ++du) {
        const int up = u + du - 1;
        if (up < 0 || up >= 5) continue;              // wave-uniform; zero contribution
#pragma unroll
        for (int dv = 0; dv < 3; ++dv) {
            const int vp = v + dv - 1;
            if (vp < 0 || vp >= 5) continue;          // wave-uniform; zero contribution

            const char* rb = xTb + (size_t)((b * 25 + up * 5 + vp) * 64) * XROW;
            const int p01 = du * 3 + dv;
            const bool t23 = (du == 1) || (dv == 1);  // compile-time per unrolled iter

#pragma unroll
            for (int bb = 0; bb < 3; ++bb) {
                const int rlo = (t23 || bb == 1) ? 0 : 1;
                const int rhi = (t23 || bb == 1) ? 9 : 8;
                bf16x8 R[10];                          // x-rows hb-1 .. hb+8
#pragma unroll
                for (int r = 0; r < 10; ++r) {
                    if (r < rlo || r > rhi) continue;               // compile-time
                    const int hr = hbu + r - 1;                     // scalar
                    R[r] = (hr < 0 || hr >= 64) ? zf
                         : *(const bf16x8*)(rb + (size_t)hr * XROW + lane_off + bb * 16);
                }

                // ---- T01 (acc01: rows0-7 br0, rows8-15 br1) ----
                if (bb == 1) {
                    const bf16x8 Wl0 = RL(p01 * 2 + 0);   // br0 t=0
                    const bf16x8 Wc  = RF(p01);           // br0 t=1 | br1 dw=1
                    const bf16x8 Wl2 = RL(p01 * 2 + 1);   // br0 t=2
#pragma unroll
                    for (int hh = 0; hh < 8; ++hh) {
                        acc01[hh] = mfma16(Wl0, R[0 + hh], acc01[hh]);
                        acc01[hh] = mfma16(Wc,  R[1 + hh], acc01[hh]);
                        acc01[hh] = mfma16(Wl2, R[2 + hh], acc01[hh]);
                    }
                } else {
                    const bf16x8 Wh = RH(p01 * 2 + (bb == 2 ? 1 : 0));  // br1 dw=0/2
#pragma unroll
                    for (int hh = 0; hh < 8; ++hh)
                        acc01[hh] = mfma16(Wh, R[1 + hh], acc01[hh]);
                }

                // ---- T23 (acc23: rows0-7 br2, rows8-15 br3) ----
                if (du == 1 && dv == 1) {
#pragma unroll
                    for (int a = 0; a < 3; ++a) {
                        const int idx = a * 3 + bb;                  // 0..8
                        const bf16x8 Wf = (idx < 6) ? RF(9 + idx) : GF(idx - 6);
#pragma unroll
                        for (int hh = 0; hh < 8; ++hh)
                            acc23[hh] = mfma16(Wf, R[a + hh], acc23[hh]);
                    }
                } else if (dv == 1) {                 // br2 only (du = 0 or 2)
#pragma unroll
                    for (int a = 0; a < 3; ++a) {
                        const bf16x8 Wl = RL(18 + (du == 2 ? 9 : 0) + a * 3 + bb);
#pragma unroll
                        for (int hh = 0; hh < 8; ++hh)
                            acc23[hh] = mfma16(Wl, R[a + hh], acc23[hh]);
                    }
                } else if (du == 1) {                 // br3 only (dv = 0 or 2)
#pragma unroll
                    for (int a = 0; a < 3; ++a) {
                        const bf16x8 Wh = RH(18 + (dv == 2 ? 9 : 0) + a * 3 + bb);
#pragma unroll
                        for (int hh = 0; hh < 8; ++hh)
                            acc23[hh] = mfma16(Wh, R[a + hh], acc23[hh]);
                    }
                }
            }
        }
    }

    // ---------------- epilogue: bias + PReLU + store (all lanes useful) ----------------
    const int qh = q >> 1;     // 0: low branch of pair, 1: high branch
    const int ql = q & 1;
    const float* bp0 = qh ? bb1 : bb0;
    const float* bp1 = qh ? bb3 : bb2;
    const float al0 = qh ? aa1[0] : aa0[0];
    const float al1 = qh ? aa3[0] : aa2[0];
    const f32x4 bv0 = *(const f32x4*)(bp0 + ql * 4);
    const f32x4 bv1 = *(const f32x4*)(bp1 + ql * 4);

    float* op = out + (size_t)b * SB_ + (size_t)u * SU_ + (size_t)v * SV_ + w0 + n;
#pragma unroll
    for (int hh = 0; hh < 8; ++hh) {
        const int h = hbu + hh;
#pragma unroll
        for (int r = 0; r < 4; ++r) {
            // pair 0 -> channels 0..15 (br0|br1)
            float v0 = acc01[hh][r] + bv0[r];
            v0 = (v0 >= 0.f) ? v0 : al0 * v0;
            op[(size_t)(q * 4 + r) * SC_ + (size_t)h * 64] = v0;
            // pair 1 -> channels 16..31 (br2|br3)
            float v1 = acc23[hh][r] + bv1[r];
            v1 = (v1 >= 0.f) ? v1 : al1 * v1;
            op[(size_t)(16 + q * 4 + r) * SC_ + (size_t)h * 64] = v1;
        }
    }
}

extern "C" void kernel_launch(void* const* d_in, const int* in_sizes, int n_in,
                              void* d_out, int out_size, void* d_ws, size_t ws_size,
                              hipStream_t stream) {
    const float* x  = (const float*)d_in[0];
    const float* w0 = (const float*)d_in[1];
    const float* b0 = (const float*)d_in[2];
    const float* a0 = (const float*)d_in[3];
    const float* w1 = (const float*)d_in[4];
    const float* b1 = (const float*)d_in[5];
    const float* a1 = (const float*)d_in[6];
    const float* w2 = (const float*)d_in[7];
    const float* b2 = (const float*)d_in[8];
    const float* a2 = (const float*)d_in[9];
    const float* w3 = (const float*)d_in[10];
    const float* b3 = (const float*)d_in[11];
    const float* a3 = (const float*)d_in[12];
    float* out = (float*)d_out;

    unsigned short* xT = (unsigned short*)d_ws;
    unsigned short* bt = (unsigned short*)((char*)d_ws + BT_OFF);

    k_prep<<<3200 + 90, 256, 0, stream>>>(x, xT, w0, w1, w2, w3, bt);  // transpose + table
    k_main<<<800, 512, 0, stream>>>(                                   // 8b x 25buv x 4hs
        xT, bt, b0, a0, b1, a1, b2, a2, b3, a3, out);
}

// Round 7
// 277.305 us; speedup vs baseline: 1.2125x; 1.2125x over previous
//
#include <hip/hip_runtime.h>

// ---------------- problem constants ----------------
#define B_  8
#define C_  32
#define U_  5
#define V_  5
#define H_  64
#define W_  64

// x / out strides (fp32 elements): [B][32][U][V][H][W]
#define SV_ 4096
#define SU_ 20480
#define SC_ 102400
#define SB_ 3276800

// xT (bf16, padded): [row = ((b*25+u*5+v)*64+h)][cq(4)][wslot(66)][c8(8)]
//   wslot = w+1 ; slots 0 and 65 are zeros (SAME padding in w for free)
//   row stride = 4*66*16 = 4224 B ; total 12800*4224 = 54067200 B
//
// Weight table (paired A-frags, rows0-7 = branch lo, rows8-15 = branch hi) -- R2 layout:
//   FULL  [0, 18432):      18 frags x 1024 B, layout [q(4)][row(16)][j(8)]
//     f 0..8  : T01 center (t=1 | dw=1): rows0-7 br0(du,dv,1), rows8-15 br1(du,dv,1)
//     f 9..17 : T23 center (du=1,dv=1) idx=a*3+bb: rows0-7 br2, rows8-15 br3
//   LO    [18432, 37440):  36 frags x 528 B = 512 data [q][oc8][j8] + 16 B zero pad
//     g 0..17 : T01 br0 singles (du,dv)x{t=0,t=2}   (rows8-15 lanes read the pad)
//     g 18..35: T23 br2 singles (dv==1, du in {0,2}) x (a,b)
//   HI    [37440, 56448):  36 frags x 528 B          (rows0-7 lanes read the pad)
//     g 0..17 : T01 br1 singles (du,dv)x{dw=0,dw=2}
//     g 18..35: T23 br3 singles (du==1, dv in {0,2}) x (a,b)
#define XROW 4224
#define BT_OFF 54067200ull
#define BT_BYTES 56448
#define LO_BASE 18432
#define HI_BASE 37440

typedef short bf16x8 __attribute__((ext_vector_type(8)));
typedef float f32x4 __attribute__((ext_vector_type(4)));

__device__ __forceinline__ unsigned short f2bf(float f) {
    unsigned int u = __builtin_bit_cast(unsigned int, f);
    u = (u + 0x7FFFu + ((u >> 16) & 1u)) >> 16;   // RNE
    return (unsigned short)u;
}

__device__ __forceinline__ f32x4 mfma16(bf16x8 a, bf16x8 b, f32x4 c) {
    return __builtin_amdgcn_mfma_f32_16x16x32_bf16(a, b, c, 0, 0, 0);
}

// ---------------- K1: prep = transpose (blocks 0..3199) + weight table (3200..3289) ----
__global__ __launch_bounds__(256)
void k_prep(const float* __restrict__ x, unsigned short* __restrict__ xT,
            const float* __restrict__ w0, const float* __restrict__ w1,
            const float* __restrict__ w2, const float* __restrict__ w3,
            unsigned short* __restrict__ btab)
{
    if (blockIdx.x >= 3200) {
        const int f = blockIdx.x - 3200;   // 0..89
        const int tid = threadIdx.x;
        if (f < 18) {
            // FULL frag: 512 entries [q][row16][j8], byte base f*1024
            for (int e = tid; e < 512; e += 256) {
                const int q = e >> 7, row = (e >> 3) & 15, j = e & 7;
                const int c = q * 8 + j;
                float val;
                if (f < 9) {          // T01 center: du=f/3, dv=f%3, tap *,*,1
                    const int tap = (f / 3) * 9 + (f % 3) * 3 + 1;
                    val = (row < 8) ? w0[row * 864 + c * 27 + tap]
                                    : w1[(row - 8) * 864 + c * 27 + tap];
                } else {              // T23 center: du=dv=1, tap 1,a,b  (idx = f-9)
                    const int tap = 9 + (f - 9);
                    val = (row < 8) ? w2[row * 864 + c * 27 + tap]
                                    : w3[(row - 8) * 864 + c * 27 + tap];
                }
                btab[f * 512 + e] = f2bf(val);
            }
        } else {
            const bool hi = (f >= 54);
            const int g = hi ? (f - 54) : (f - 18);        // 0..35
            const size_t base = (hi ? HI_BASE : LO_BASE) / 2 + (size_t)g * 264;
            for (int e = tid; e < 264; e += 256) {
                unsigned short outv = 0;                    // zero pad entries 256..263
                if (e < 256) {
                    const int q = e >> 6, oc = (e >> 3) & 7, j = e & 7;
                    const int c = q * 8 + j;
                    float val;
                    if (g < 18) {     // T01 singles: pair p=(du,dv), tap offset which*2
                        const int p = g >> 1, which = g & 1;
                        const int tap = (p / 3) * 9 + (p % 3) * 3 + which * 2;
                        val = hi ? w1[oc * 864 + c * 27 + tap]      // br1, dw=0/2
                                 : w0[oc * 864 + c * 27 + tap];     // br0, t =0/2
                    } else {          // T23 singles: outer = 0 or 2, tap outer,a,b
                        const int h2 = g - 18;
                        const int tap = (h2 / 9) * 18 + (h2 % 9);   // outer*9 + a*3+b
                        val = hi ? w3[oc * 864 + c * 27 + tap]      // br3 (du==1)
                                 : w2[oc * 864 + c * 27 + tap];     // br2 (dv==1)
                    }
                    outv = f2bf(val);
                }
                btab[base + e] = outv;
            }
        }
        return;
    }

    // ---- x fp32 [B,C,U,V,H,W] -> padded bf16 xT ----
    __shared__ float tl[C_ * 4 * 64];   // [c][h(4)][w(64)] fp32, 32 KB
    const int tid = threadIdx.x;
    int blk = blockIdx.x;
    const int hq = blk & 15; blk >>= 4;
    const int v = blk % 5; blk /= 5;
    const int u = blk % 5;
    const int b = blk / 5;
    const int h0 = hq * 4;

    const float* src = x + (size_t)b * SB_ + (size_t)u * SU_ + (size_t)v * SV_ + h0 * 64;
#pragma unroll
    for (int i = 0; i < 8; ++i) {
        const int e = tid + i * 256;
        const int c = e >> 6;
        const int rem = e & 63;
        const int h = rem >> 4;
        const int w4 = (rem & 15) * 4;
        const float4 val = *(const float4*)(src + (size_t)c * SC_ + h * 64 + w4);
        *(float4*)(tl + c * 256 + h * 64 + w4) = val;
    }
    __syncthreads();

    const int h = tid >> 6;
    const int w = tid & 63;
    unsigned short* dst = xT + (size_t)((b * 25 + u * 5 + v) * 64 + h0 + h) * (XROW / 2);
    const uint4 z = make_uint4(0u, 0u, 0u, 0u);
#pragma unroll
    for (int cq = 0; cq < 4; ++cq) {
        unsigned short s[8];
#pragma unroll
        for (int j = 0; j < 8; ++j)
            s[j] = f2bf(tl[(cq * 8 + j) * 256 + h * 64 + w]);
        uint4 o;
        o.x = (unsigned)s[0] | ((unsigned)s[1] << 16);
        o.y = (unsigned)s[2] | ((unsigned)s[3] << 16);
        o.z = (unsigned)s[4] | ((unsigned)s[5] << 16);
        o.w = (unsigned)s[6] | ((unsigned)s[7] << 16);
        *(uint4*)(dst + cq * 528 + (w + 1) * 8) = o;           // wslot = w+1
        if (w == 0)  *(uint4*)(dst + cq * 528 + 0)       = z;  // wslot 0
        if (w == 63) *(uint4*)(dst + cq * 528 + 65 * 8)  = z;  // wslot 65
    }
}

// ---------------- branch-free tap loop, templated on valid (du,dv) ranges ----------------
// Straight-line load/MFMA sequence per (u,v)-class: no wave-uniform continues, so the
// scheduler can hoist F-loads across pair/bb boundaries (latency hiding without occupancy).
template<int DU0, int DU1, int DV0, int DV1>
__device__ __forceinline__ void tap_loop(
    const char* __restrict__ xTb, const char* __restrict__ wlds,
    int rowblk, int u, int v, int hbu, int lane_off,
    int off_full, int off_lo, int off_hi,
    f32x4* __restrict__ acc01, f32x4* __restrict__ acc23)
{
    const bf16x8 zf = {0, 0, 0, 0, 0, 0, 0, 0};
    auto RF = [&](int f) -> bf16x8 {
        return *(const bf16x8*)(wlds + f * 1024 + off_full);
    };
    auto RL = [&](int g) -> bf16x8 {
        return *(const bf16x8*)(wlds + LO_BASE + g * 528 + off_lo);
    };
    auto RH = [&](int g) -> bf16x8 {
        return *(const bf16x8*)(wlds + HI_BASE + g * 528 + off_hi);
    };

#pragma unroll
    for (int du = DU0; du <= DU1; ++du) {
        const int up = u + du - 1;                    // in range by template contract
#pragma unroll
        for (int dv = DV0; dv <= DV1; ++dv) {
            const int vp = v + dv - 1;                // in range by template contract

            const char* rb = xTb + (size_t)((rowblk + up * 5 + vp) * 64) * XROW;
            const int p01 = du * 3 + dv;
            const bool t23 = (du == 1) || (dv == 1);  // compile-time per unrolled iter

#pragma unroll
            for (int bb = 0; bb < 3; ++bb) {
                const int rlo = (t23 || bb == 1) ? 0 : 1;
                const int rhi = (t23 || bb == 1) ? 5 : 4;
                bf16x8 F[6];
#pragma unroll
                for (int r = 0; r < 6; ++r) {
                    if (r < rlo || r > rhi) continue;               // compile-time
                    const int hr = hbu + r - 1;                     // scalar
                    F[r] = (hr < 0 || hr >= 64) ? zf
                         : *(const bf16x8*)(rb + (size_t)hr * XROW + lane_off + bb * 16);
                }

                // ---- T01 (acc01: rows0-7 br0, rows8-15 br1) ----
                if (bb == 1) {
                    const bf16x8 Wl0 = RL(p01 * 2 + 0);   // br0 t=0
                    const bf16x8 Wc  = RF(p01);           // br0 t=1 | br1 dw=1
                    const bf16x8 Wl2 = RL(p01 * 2 + 1);   // br0 t=2
#pragma unroll
                    for (int hh = 0; hh < 4; ++hh) {
                        acc01[hh] = mfma16(Wl0, F[0 + hh], acc01[hh]);
                        acc01[hh] = mfma16(Wc,  F[1 + hh], acc01[hh]);
                        acc01[hh] = mfma16(Wl2, F[2 + hh], acc01[hh]);
                    }
                } else {
                    const bf16x8 Wh = RH(p01 * 2 + (bb == 2 ? 1 : 0));  // br1 dw=0/2
#pragma unroll
                    for (int hh = 0; hh < 4; ++hh)
                        acc01[hh] = mfma16(Wh, F[1 + hh], acc01[hh]);
                }

                // ---- T23 (acc23: rows0-7 br2, rows8-15 br3) ----
                if (du == 1 && dv == 1) {
#pragma unroll
                    for (int a = 0; a < 3; ++a) {
                        const bf16x8 Wf = RF(9 + a * 3 + bb);
#pragma unroll
                        for (int hh = 0; hh < 4; ++hh)
                            acc23[hh] = mfma16(Wf, F[a + hh], acc23[hh]);
                    }
                } else if (dv == 1) {                 // br2 only (du = 0 or 2)
#pragma unroll
                    for (int a = 0; a < 3; ++a) {
                        const bf16x8 Wl = RL(18 + (du == 2 ? 9 : 0) + a * 3 + bb);
#pragma unroll
                        for (int hh = 0; hh < 4; ++hh)
                            acc23[hh] = mfma16(Wl, F[a + hh], acc23[hh]);
                    }
                } else if (du == 1) {                 // br3 only (dv = 0 or 2)
#pragma unroll
                    for (int a = 0; a < 3; ++a) {
                        const bf16x8 Wh = RH(18 + (dv == 2 ? 9 : 0) + a * 3 + bb);
#pragma unroll
                        for (int hh = 0; hh < 4; ++hh)
                            acc23[hh] = mfma16(Wh, F[a + hh], acc23[hh]);
                    }
                }
            }
        }
    }
}

// ---------------- K2: main MFMA kernel (9-case static control flow) ----------------
// grid 1600 = 8 b * 25 buv * 8 hs ; block 512 thr = 8 waves
// XCD-chunked: XCD (blk&7) owns batch b=(blk&7); hs fastest keeps (u,v) 9-neighborhood
// in that XCD's L2. wave: w-tile (wave&3)*16, h-quad rbase=(wave>>2)*4.
// A rows0-7 / 8-15 carry two branches -> acc01 (br0|br1), acc23 (br2|br3).
// launch_bounds(512,4): cap 128 unified regs -- ABOVE expected demand (~100-125).
// R3/R6 lesson: a cap below natural demand spills catastrophically; (512,2) risks
// an occupancy cliff if hoisting pushes past 128. Watch WRITE_SIZE for spill.
__global__ __launch_bounds__(512, 4)
void k_main(const unsigned short* __restrict__ xT,
            const unsigned short* __restrict__ btabu,
            const float* __restrict__ bb0, const float* __restrict__ aa0,
            const float* __restrict__ bb1, const float* __restrict__ aa1,
            const float* __restrict__ bb2, const float* __restrict__ aa2,
            const float* __restrict__ bb3, const float* __restrict__ aa3,
            float* __restrict__ out)
{
    __shared__ alignas(16) char wlds[BT_BYTES];

    const int tid = threadIdx.x;
    const int blk = blockIdx.x;
    const int b   = blk & 7;          // == XCD id
    const int i   = blk >> 3;         // 0..199
    const int buv = i >> 3;           // 0..24
    const int hs  = i & 7;
    const int v = buv % 5;
    const int u = buv / 5;
    const int h0 = hs * 8;

    // stage weight table to LDS (one time): 56448/16 = 3528 uint4
    {
        const uint4* g = (const uint4*)btabu;
        uint4* l = (uint4*)wlds;
#pragma unroll
        for (int it = 0; it < 7; ++it) {
            const int e = tid + it * 512;
            if (e < 3528) l[e] = g[e];
        }
    }
    __syncthreads();   // the only barrier

    const int wave = tid >> 6;
    const int lane = tid & 63;
    const int n = lane & 15;
    const int q = lane >> 4;
    const int w0 = (wave & 3) * 16;
    const int hb = h0 + (wave >> 2) * 4;
    const int hbu = __builtin_amdgcn_readfirstlane(hb);   // wave-uniform -> SGPR

    f32x4 acc01[4], acc23[4];
#pragma unroll
    for (int j = 0; j < 4; ++j) { acc01[j] = (f32x4)0.f; acc23[j] = (f32x4)0.f; }

    const char* xTb = (const char*)xT;
    const int lane_off = q * 1056 + (w0 + n) * 16;

    // per-lane A-frag offsets (computed once; frag index folds to imm offset)
    const int off_full = q * 256 + n * 16;                           // FULL [q][row16][j]
    const int off_lo   = (n < 8) ? (q * 128 + n * 16) : 512;         // data | frag zero pad
    const int off_hi   = (n < 8) ? 512 : (q * 128 + (n & 7) * 16);   // frag zero pad | data

    const int rowblk = b * 25;
    const int uc = (u == 0) ? 0 : (u == 4 ? 2 : 1);
    const int vc = (v == 0) ? 0 : (v == 4 ? 2 : 1);

#define TAPS(A,B,C,D) tap_loop<A,B,C,D>(xTb, wlds, rowblk, u, v, hbu, lane_off, \
                                        off_full, off_lo, off_hi, acc01, acc23)
    switch (uc * 3 + vc) {
        case 0: TAPS(1, 2, 1, 2); break;   // u=0, v=0
        case 1: TAPS(1, 2, 0, 2); break;   // u=0, v mid
        case 2: TAPS(1, 2, 0, 1); break;   // u=0, v=4
        case 3: TAPS(0, 2, 1, 2); break;   // u mid, v=0
        case 4: TAPS(0, 2, 0, 2); break;   // interior
        case 5: TAPS(0, 2, 0, 1); break;   // u mid, v=4
        case 6: TAPS(0, 1, 1, 2); break;   // u=4, v=0
        case 7: TAPS(0, 1, 0, 2); break;   // u=4, v mid
        case 8: TAPS(0, 1, 0, 1); break;   // u=4, v=4
    }
#undef TAPS

    // ---------------- epilogue: bias + PReLU + store (all lanes useful) ----------------
    const int qh = q >> 1;     // 0: low branch of pair, 1: high branch
    const int ql = q & 1;
    const float* bp0 = qh ? bb1 : bb0;
    const float* bp1 = qh ? bb3 : bb2;
    const float al0 = qh ? aa1[0] : aa0[0];
    const float al1 = qh ? aa3[0] : aa2[0];
    const f32x4 bv0 = *(const f32x4*)(bp0 + ql * 4);
    const f32x4 bv1 = *(const f32x4*)(bp1 + ql * 4);

    float* op = out + (size_t)b * SB_ + (size_t)u * SU_ + (size_t)v * SV_ + w0 + n;
#pragma unroll
    for (int hh = 0; hh < 4; ++hh) {
        const int h = hbu + hh;
#pragma unroll
        for (int r = 0; r < 4; ++r) {
            // pair 0 -> channels 0..15 (br0|br1)
            float v0 = acc01[hh][r] + bv0[r];
            v0 = (v0 >= 0.f) ? v0 : al0 * v0;
            op[(size_t)(q * 4 + r) * SC_ + (size_t)h * 64] = v0;
            // pair 1 -> channels 16..31 (br2|br3)
            float v1 = acc23[hh][r] + bv1[r];
            v1 = (v1 >= 0.f) ? v1 : al1 * v1;
            op[(size_t)(16 + q * 4 + r) * SC_ + (size_t)h * 64] = v1;
        }
    }
}

extern "C" void kernel_launch(void* const* d_in, const int* in_sizes, int n_in,
                              void* d_out, int out_size, void* d_ws, size_t ws_size,
                              hipStream_t stream) {
    const float* x  = (const float*)d_in[0];
    const float* w0 = (const float*)d_in[1];
    const float* b0 = (const float*)d_in[2];
    const float* a0 = (const float*)d_in[3];
    const float* w1 = (const float*)d_in[4];
    const float* b1 = (const float*)d_in[5];
    const float* a1 = (const float*)d_in[6];
    const float* w2 = (const float*)d_in[7];
    const float* b2 = (const float*)d_in[8];
    const float* a2 = (const float*)d_in[9];
    const float* w3 = (const float*)d_in[10];
    const float* b3 = (const float*)d_in[11];
    const float* a3 = (const float*)d_in[12];
    float* out = (float*)d_out;

    unsigned short* xT = (unsigned short*)d_ws;
    unsigned short* bt = (unsigned short*)((char*)d_ws + BT_OFF);

    k_prep<<<3200 + 90, 256, 0, stream>>>(x, xT, w0, w1, w2, w3, bt);  // transpose + table
    k_main<<<1600, 512, 0, stream>>>(                                  // 8b x 25buv x 8hs
        xT, bt, b0, a0, b1, a1, b2, a2, b3, a3, out);
}

// Round 9
// 276.435 us; speedup vs baseline: 1.2164x; 1.0031x over previous
//
#include <hip/hip_runtime.h>

// ---------------- problem constants ----------------
#define B_  8
#define C_  32
#define U_  5
#define V_  5
#define H_  64
#define W_  64

// x / out strides (fp32 elements): [B][32][U][V][H][W]
#define SV_ 4096
#define SU_ 20480
#define SC_ 102400
#define SB_ 3276800

// xT (bf16, padded): [row = ((b*25+u*5+v)*64+h)][cq(4)][wslot(66)][c8(8)]
//   wslot = w+1 ; slots 0 and 65 are zeros (SAME padding in w for free)
//   row stride = 4*66*16 = 4224 B ; total 12800*4224 = 54067200 B
//
// Weight table (paired A-frags, rows0-7 = branch lo, rows8-15 = branch hi) -- R2 layout:
//   FULL  [0, 18432):      18 frags x 1024 B, layout [q(4)][row(16)][j(8)]
//     f 0..8  : T01 center (t=1 | dw=1): rows0-7 br0(du,dv,1), rows8-15 br1(du,dv,1)
//     f 9..17 : T23 center (du=1,dv=1) idx=a*3+bb: rows0-7 br2, rows8-15 br3
//   LO    [18432, 37440):  36 frags x 528 B = 512 data [q][oc8][j8] + 16 B zero pad
//     g 0..17 : T01 br0 singles (du,dv)x{t=0,t=2}   (rows8-15 lanes read the pad)
//     g 18..35: T23 br2 singles (dv==1, du in {0,2}) x (a,b)
//   HI    [37440, 56448):  36 frags x 528 B          (rows0-7 lanes read the pad)
//     g 0..17 : T01 br1 singles (du,dv)x{dw=0,dw=2}
//     g 18..35: T23 br3 singles (du==1, dv in {0,2}) x (a,b)
#define XROW 4224
#define BT_OFF 54067200ull
#define BT_BYTES 56448
#define LO_BASE 18432
#define HI_BASE 37440

typedef short bf16x8 __attribute__((ext_vector_type(8)));
typedef float f32x4 __attribute__((ext_vector_type(4)));

__device__ __forceinline__ unsigned short f2bf(float f) {
    unsigned int u = __builtin_bit_cast(unsigned int, f);
    u = (u + 0x7FFFu + ((u >> 16) & 1u)) >> 16;   // RNE
    return (unsigned short)u;
}

__device__ __forceinline__ f32x4 mfma16(bf16x8 a, bf16x8 b, f32x4 c) {
    return __builtin_amdgcn_mfma_f32_16x16x32_bf16(a, b, c, 0, 0, 0);
}

// ---------------- K1: prep = transpose (blocks 0..3199) + weight table (3200..3289) ----
__global__ __launch_bounds__(256)
void k_prep(const float* __restrict__ x, unsigned short* __restrict__ xT,
            const float* __restrict__ w0, const float* __restrict__ w1,
            const float* __restrict__ w2, const float* __restrict__ w3,
            unsigned short* __restrict__ btab)
{
    if (blockIdx.x >= 3200) {
        const int f = blockIdx.x - 3200;   // 0..89
        const int tid = threadIdx.x;
        if (f < 18) {
            // FULL frag: 512 entries [q][row16][j8], byte base f*1024
            for (int e = tid; e < 512; e += 256) {
                const int q = e >> 7, row = (e >> 3) & 15, j = e & 7;
                const int c = q * 8 + j;
                float val;
                if (f < 9) {          // T01 center: du=f/3, dv=f%3, tap *,*,1
                    const int tap = (f / 3) * 9 + (f % 3) * 3 + 1;
                    val = (row < 8) ? w0[row * 864 + c * 27 + tap]
                                    : w1[(row - 8) * 864 + c * 27 + tap];
                } else {              // T23 center: du=dv=1, tap 1,a,b  (idx = f-9)
                    const int tap = 9 + (f - 9);
                    val = (row < 8) ? w2[row * 864 + c * 27 + tap]
                                    : w3[(row - 8) * 864 + c * 27 + tap];
                }
                btab[f * 512 + e] = f2bf(val);
            }
        } else {
            const bool hi = (f >= 54);
            const int g = hi ? (f - 54) : (f - 18);        // 0..35
            const size_t base = (hi ? HI_BASE : LO_BASE) / 2 + (size_t)g * 264;
            for (int e = tid; e < 264; e += 256) {
                unsigned short outv = 0;                    // zero pad entries 256..263
                if (e < 256) {
                    const int q = e >> 6, oc = (e >> 3) & 7, j = e & 7;
                    const int c = q * 8 + j;
                    float val;
                    if (g < 18) {     // T01 singles: pair p=(du,dv), tap offset which*2
                        const int p = g >> 1, which = g & 1;
                        const int tap = (p / 3) * 9 + (p % 3) * 3 + which * 2;
                        val = hi ? w1[oc * 864 + c * 27 + tap]      // br1, dw=0/2
                                 : w0[oc * 864 + c * 27 + tap];     // br0, t =0/2
                    } else {          // T23 singles: outer = 0 or 2, tap outer,a,b
                        const int h2 = g - 18;
                        const int tap = (h2 / 9) * 18 + (h2 % 9);   // outer*9 + a*3+b
                        val = hi ? w3[oc * 864 + c * 27 + tap]      // br3 (du==1)
                                 : w2[oc * 864 + c * 27 + tap];     // br2 (dv==1)
                    }
                    outv = f2bf(val);
                }
                btab[base + e] = outv;
            }
        }
        return;
    }

    // ---- x fp32 [B,C,U,V,H,W] -> padded bf16 xT ----
    __shared__ float tl[C_ * 4 * 64];   // [c][h(4)][w(64)] fp32, 32 KB
    const int tid = threadIdx.x;
    int blk = blockIdx.x;
    const int hq = blk & 15; blk >>= 4;
    const int v = blk % 5; blk /= 5;
    const int u = blk % 5;
    const int b = blk / 5;
    const int h0 = hq * 4;

    const float* src = x + (size_t)b * SB_ + (size_t)u * SU_ + (size_t)v * SV_ + h0 * 64;
#pragma unroll
    for (int i = 0; i < 8; ++i) {
        const int e = tid + i * 256;
        const int c = e >> 6;
        const int rem = e & 63;
        const int h = rem >> 4;
        const int w4 = (rem & 15) * 4;
        const float4 val = *(const float4*)(src + (size_t)c * SC_ + h * 64 + w4);
        *(float4*)(tl + c * 256 + h * 64 + w4) = val;
    }
    __syncthreads();

    const int h = tid >> 6;
    const int w = tid & 63;
    unsigned short* dst = xT + (size_t)((b * 25 + u * 5 + v) * 64 + h0 + h) * (XROW / 2);
    const uint4 z = make_uint4(0u, 0u, 0u, 0u);
#pragma unroll
    for (int cq = 0; cq < 4; ++cq) {
        unsigned short s[8];
#pragma unroll
        for (int j = 0; j < 8; ++j)
            s[j] = f2bf(tl[(cq * 8 + j) * 256 + h * 64 + w]);
        uint4 o;
        o.x = (unsigned)s[0] | ((unsigned)s[1] << 16);
        o.y = (unsigned)s[2] | ((unsigned)s[3] << 16);
        o.z = (unsigned)s[4] | ((unsigned)s[5] << 16);
        o.w = (unsigned)s[6] | ((unsigned)s[7] << 16);
        *(uint4*)(dst + cq * 528 + (w + 1) * 8) = o;           // wslot = w+1
        if (w == 0)  *(uint4*)(dst + cq * 528 + 0)       = z;  // wslot 0
        if (w == 63) *(uint4*)(dst + cq * 528 + 65 * 8)  = z;  // wslot 65
    }
}

// ---------------- software-pipelined tap sequence, templated on (du,dv) ranges -------
// Steps s = 0..NS-1 map to (du,dv,bb). Ping-pong F buffers: while step s computes
// from one buffer, step s+1's global loads are ISSUED into the other. A
// sched_barrier(0) between the load block and the MFMA block stops the scheduler
// from sinking the prefetch back to first-use (R7 showed it will: VGPR stayed 52).
// The waitcnt before step-s MFMAs is then a counted vmcnt (loads landed one full
// MFMA block ago), never a drain -- T3/T4 in-register, no barriers needed.
template<int DU0, int DU1, int DV0, int DV1>
__device__ __forceinline__ void tap_loop(
    const char* __restrict__ xTb, const char* __restrict__ wlds,
    int rowblk, int u, int v, int hbu, int lane_off,
    int off_full, int off_lo, int off_hi,
    f32x4* __restrict__ acc01, f32x4* __restrict__ acc23)
{
    constexpr int NDV = DV1 - DV0 + 1;
    constexpr int NP  = (DU1 - DU0 + 1) * NDV;
    constexpr int NS  = NP * 3;

    const bf16x8 zf = {0, 0, 0, 0, 0, 0, 0, 0};
    auto RF = [&](int f) -> bf16x8 {
        return *(const bf16x8*)(wlds + f * 1024 + off_full);
    };
    auto RL = [&](int g) -> bf16x8 {
        return *(const bf16x8*)(wlds + LO_BASE + g * 528 + off_lo);
    };
    auto RH = [&](int g) -> bf16x8 {
        return *(const bf16x8*)(wlds + HI_BASE + g * 528 + off_hi);
    };

    // step decode -- s is always an unroll-time constant at call sites
    auto SDU = [&](int s) { return DU0 + (s / 3) / NDV; };
    auto SDV = [&](int s) { return DV0 + (s / 3) % NDV; };

    // issue the global loads of step s into F (addresses wave-uniform-base + lane off)
    auto LOAD = [&](bf16x8 (&F)[6], int s) {
        const int du = SDU(s), dv = SDV(s), bb = s % 3;
        const int up = u + du - 1, vp = v + dv - 1;
        const char* rb = xTb + (size_t)((rowblk + up * 5 + vp) * 64) * XROW;
        const bool t23 = (du == 1) || (dv == 1);
        const int rlo = (t23 || bb == 1) ? 0 : 1;
        const int rhi = (t23 || bb == 1) ? 5 : 4;
#pragma unroll
        for (int r = 0; r < 6; ++r) {
            if (r < rlo || r > rhi) continue;               // folds: s,r constants
            const int hr = hbu + r - 1;                     // scalar
            F[r] = (hr < 0 || hr >= 64) ? zf
                 : *(const bf16x8*)(rb + (size_t)hr * XROW + lane_off + bb * 16);
        }
    };

    // MFMA block of step s, consuming F (weight ds_reads + matrix ops)
    auto STEP = [&](const bf16x8 (&F)[6], int s) {
        const int du = SDU(s), dv = SDV(s), bb = s % 3;
        const int p01 = du * 3 + dv;

        // ---- T01 (acc01: rows0-7 br0, rows8-15 br1) ----
        if (bb == 1) {
            const bf16x8 Wl0 = RL(p01 * 2 + 0);   // br0 t=0
            const bf16x8 Wc  = RF(p01);           // br0 t=1 | br1 dw=1
            const bf16x8 Wl2 = RL(p01 * 2 + 1);   // br0 t=2
#pragma unroll
            for (int hh = 0; hh < 4; ++hh) {
                acc01[hh] = mfma16(Wl0, F[0 + hh], acc01[hh]);
                acc01[hh] = mfma16(Wc,  F[1 + hh], acc01[hh]);
                acc01[hh] = mfma16(Wl2, F[2 + hh], acc01[hh]);
            }
        } else {
            const bf16x8 Wh = RH(p01 * 2 + (bb == 2 ? 1 : 0));  // br1 dw=0/2
#pragma unroll
            for (int hh = 0; hh < 4; ++hh)
                acc01[hh] = mfma16(Wh, F[1 + hh], acc01[hh]);
        }

        // ---- T23 (acc23: rows0-7 br2, rows8-15 br3) ----
        if (du == 1 && dv == 1) {
#pragma unroll
            for (int a = 0; a < 3; ++a) {
                const bf16x8 Wf = RF(9 + a * 3 + bb);
#pragma unroll
                for (int hh = 0; hh < 4; ++hh)
                    acc23[hh] = mfma16(Wf, F[a + hh], acc23[hh]);
            }
        } else if (dv == 1) {                 // br2 only (du = 0 or 2)
#pragma unroll
            for (int a = 0; a < 3; ++a) {
                const bf16x8 Wl = RL(18 + (du == 2 ? 9 : 0) + a * 3 + bb);
#pragma unroll
                for (int hh = 0; hh < 4; ++hh)
                    acc23[hh] = mfma16(Wl, F[a + hh], acc23[hh]);
            }
        } else if (du == 1) {                 // br3 only (dv = 0 or 2)
#pragma unroll
            for (int a = 0; a < 3; ++a) {
                const bf16x8 Wh = RH(18 + (dv == 2 ? 9 : 0) + a * 3 + bb);
#pragma unroll
                for (int hh = 0; hh < 4; ++hh)
                    acc23[hh] = mfma16(Wh, F[a + hh], acc23[hh]);
            }
        }
    };

    bf16x8 FA[6], FB[6];
#pragma unroll
    for (int r = 0; r < 6; ++r) { FA[r] = zf; FB[r] = zf; }

    LOAD(FA, 0);                               // prologue
#pragma unroll
    for (int s2 = 0; s2 < NS; s2 += 2) {       // 2-step manual unroll: no buffer copies
        if (s2 + 1 < NS) LOAD(FB, s2 + 1);
        __builtin_amdgcn_sched_barrier(0);     // keep prefetch above the MFMAs
        STEP(FA, s2);
        if (s2 + 1 < NS) {
            if (s2 + 2 < NS) LOAD(FA, s2 + 2);
            __builtin_amdgcn_sched_barrier(0);
            STEP(FB, s2 + 1);
        }
    }
}

// ---------------- K2: main MFMA kernel (9-case static control flow, SW pipeline) -----
// grid 1600 = 8 b * 25 buv * 8 hs ; block 512 thr = 8 waves
// XCD-chunked: XCD (blk&7) owns batch b=(blk&7); hs fastest keeps (u,v) 9-neighborhood
// in that XCD's L2. wave: w-tile (wave&3)*16, h-quad rbase=(wave>>2)*4.
// A rows0-7 / 8-15 carry two branches -> acc01 (br0|br1), acc23 (br2|br3).
// Regs: FA+FB 48 + W ~12 + acc 32 + addr ~15 = ~108 unified; launch_bounds(512,4)
// caps at 128 (above demand). Spill tripwire: WRITE_SIZE > 120 MB or VGPR = 128.
__global__ __launch_bounds__(512, 4)
void k_main(const unsigned short* __restrict__ xT,
            const unsigned short* __restrict__ btabu,
            const float* __restrict__ bb0, const float* __restrict__ aa0,
            const float* __restrict__ bb1, const float* __restrict__ aa1,
            const float* __restrict__ bb2, const float* __restrict__ aa2,
            const float* __restrict__ bb3, const float* __restrict__ aa3,
            float* __restrict__ out)
{
    __shared__ alignas(16) char wlds[BT_BYTES];

    const int tid = threadIdx.x;
    const int blk = blockIdx.x;
    const int b   = blk & 7;          // == XCD id
    const int i   = blk >> 3;         // 0..199
    const int buv = i >> 3;           // 0..24
    const int hs  = i & 7;
    const int v = buv % 5;
    const int u = buv / 5;
    const int h0 = hs * 8;

    // stage weight table to LDS (one time): 56448/16 = 3528 uint4
    {
        const uint4* g = (const uint4*)btabu;
        uint4* l = (uint4*)wlds;
#pragma unroll
        for (int it = 0; it < 7; ++it) {
            const int e = tid + it * 512;
            if (e < 3528) l[e] = g[e];
        }
    }
    __syncthreads();   // the only barrier

    const int wave = tid >> 6;
    const int lane = tid & 63;
    const int n = lane & 15;
    const int q = lane >> 4;
    const int w0 = (wave & 3) * 16;
    const int hb = h0 + (wave >> 2) * 4;
    const int hbu = __builtin_amdgcn_readfirstlane(hb);   // wave-uniform -> SGPR

    f32x4 acc01[4], acc23[4];
#pragma unroll
    for (int j = 0; j < 4; ++j) { acc01[j] = (f32x4)0.f; acc23[j] = (f32x4)0.f; }

    const char* xTb = (const char*)xT;
    const int lane_off = q * 1056 + (w0 + n) * 16;

    // per-lane A-frag offsets (computed once; frag index folds to imm offset)
    const int off_full = q * 256 + n * 16;                           // FULL [q][row16][j]
    const int off_lo   = (n < 8) ? (q * 128 + n * 16) : 512;         // data | frag zero pad
    const int off_hi   = (n < 8) ? 512 : (q * 128 + (n & 7) * 16);   // frag zero pad | data

    const int rowblk = b * 25;
    const int uc = (u == 0) ? 0 : (u == 4 ? 2 : 1);
    const int vc = (v == 0) ? 0 : (v == 4 ? 2 : 1);

#define TAPS(A,B,C,D) tap_loop<A,B,C,D>(xTb, wlds, rowblk, u, v, hbu, lane_off, \
                                        off_full, off_lo, off_hi, acc01, acc23)
    switch (uc * 3 + vc) {
        case 0: TAPS(1, 2, 1, 2); break;   // u=0, v=0
        case 1: TAPS(1, 2, 0, 2); break;   // u=0, v mid
        case 2: TAPS(1, 2, 0, 1); break;   // u=0, v=4
        case 3: TAPS(0, 2, 1, 2); break;   // u mid, v=0
        case 4: TAPS(0, 2, 0, 2); break;   // interior
        case 5: TAPS(0, 2, 0, 1); break;   // u mid, v=4
        case 6: TAPS(0, 1, 1, 2); break;   // u=4, v=0
        case 7: TAPS(0, 1, 0, 2); break;   // u=4, v mid
        case 8: TAPS(0, 1, 0, 1); break;   // u=4, v=4
    }
#undef TAPS

    // ---------------- epilogue: bias + PReLU + store (all lanes useful) ----------------
    const int qh = q >> 1;     // 0: low branch of pair, 1: high branch
    const int ql = q & 1;
    const float* bp0 = qh ? bb1 : bb0;
    const float* bp1 = qh ? bb3 : bb2;
    const float al0 = qh ? aa1[0] : aa0[0];
    const float al1 = qh ? aa3[0] : aa2[0];
    const f32x4 bv0 = *(const f32x4*)(bp0 + ql * 4);
    const f32x4 bv1 = *(const f32x4*)(bp1 + ql * 4);

    float* op = out + (size_t)b * SB_ + (size_t)u * SU_ + (size_t)v * SV_ + w0 + n;
#pragma unroll
    for (int hh = 0; hh < 4; ++hh) {
        const int h = hbu + hh;
#pragma unroll
        for (int r = 0; r < 4; ++r) {
            // pair 0 -> channels 0..15 (br0|br1)
            float v0 = acc01[hh][r] + bv0[r];
            v0 = (v0 >= 0.f) ? v0 : al0 * v0;
            op[(size_t)(q * 4 + r) * SC_ + (size_t)h * 64] = v0;
            // pair 1 -> channels 16..31 (br2|br3)
            float v1 = acc23[hh][r] + bv1[r];
            v1 = (v1 >= 0.f) ? v1 : al1 * v1;
            op[(size_t)(16 + q * 4 + r) * SC_ + (size_t)h * 64] = v1;
        }
    }
}

extern "C" void kernel_launch(void* const* d_in, const int* in_sizes, int n_in,
                              void* d_out, int out_size, void* d_ws, size_t ws_size,
                              hipStream_t stream) {
    const float* x  = (const float*)d_in[0];
    const float* w0 = (const float*)d_in[1];
    const float* b0 = (const float*)d_in[2];
    const float* a0 = (const float*)d_in[3];
    const float* w1 = (const float*)d_in[4];
    const float* b1 = (const float*)d_in[5];
    const float* a1 = (const float*)d_in[6];
    const float* w2 = (const float*)d_in[7];
    const float* b2 = (const float*)d_in[8];
    const float* a2 = (const float*)d_in[9];
    const float* w3 = (const float*)d_in[10];
    const float* b3 = (const float*)d_in[11];
    const float* a3 = (const float*)d_in[12];
    float* out = (float*)d_out;

    unsigned short* xT = (unsigned short*)d_ws;
    unsigned short* bt = (unsigned short*)((char*)d_ws + BT_OFF);

    k_prep<<<3200 + 90, 256, 0, stream>>>(x, xT, w0, w1, w2, w3, bt);  // transpose + table
    k_main<<<1600, 512, 0, stream>>>(                                  // 8b x 25buv x 8hs
        xT, bt, b0, a0, b1, a1, b2, a2, b3, a3, out);
}